// Round 1
// baseline (445.159 us; speedup 1.0000x reference)
//
#include <hip/hip_runtime.h>

// ---------------------------------------------------------------------------
// AttentionBlock (RMSNorm -> gated windowed attention -> RMSNorm -> SwiGLU FFN)
// MI355X / gfx950. Strategy: bf16 MFMA (16x16x32) for all GEMMs + attention,
// fp32 accumulate, fused epilogues. m97-structure 128x128 GEMM with
// global_load_lds width-16 double-buffered staging.
// ---------------------------------------------------------------------------

#define DEV __device__ __forceinline__

using u16 = unsigned short;
typedef __attribute__((ext_vector_type(8))) short  short8;   // 8 x bf16 (4 VGPR)
typedef __attribute__((ext_vector_type(4))) float  floatx4;

DEV u16 f2bf(float f) {                 // round-to-nearest-even fp32 -> bf16
  unsigned u = __builtin_bit_cast(unsigned, f);
  u += 0x7FFFu + ((u >> 16) & 1u);
  return (u16)(u >> 16);
}
DEV float bf2f(u16 h) {
  unsigned u = ((unsigned)h) << 16;
  return __builtin_bit_cast(float, u);
}
DEV floatx4 mfma16(short8 a, short8 b, floatx4 c) {
  return __builtin_amdgcn_mfma_f32_16x16x32_bf16(a, b, c, 0, 0, 0);
}
DEV void gload16(const u16* g, u16* lds_base_wave_uniform) {
  // async global->LDS, 16B per lane; HW writes lds_base + lane*16
  __builtin_amdgcn_global_load_lds(
      (const __attribute__((address_space(1))) void*)g,
      (__attribute__((address_space(3))) void*)lds_base_wave_uniform,
      16, 0, 0);
}

// ---------------------------------------------------------------------------
// fp32 -> bf16 weight conversion (each thread converts one float4)
// ---------------------------------------------------------------------------
__global__ __launch_bounds__(256) void cvt_k(const float* __restrict__ in,
                                             u16* __restrict__ o) {
  const size_t i = (size_t)blockIdx.x * 256 + threadIdx.x;
  const float4 v = ((const float4*)in)[i];
  ushort4 r;
  r.x = f2bf(v.x); r.y = f2bf(v.y); r.z = f2bf(v.z); r.w = f2bf(v.w);
  ((ushort4*)o)[i] = r;
}

// ---------------------------------------------------------------------------
// RMSNorm: one block per row (1024 cols), fp32 in -> bf16 out
// ---------------------------------------------------------------------------
__global__ __launch_bounds__(256) void rmsnorm_k(const float* __restrict__ x,
                                                 const float* __restrict__ wt,
                                                 u16* __restrict__ o) {
  __shared__ float red[4];
  const int row = blockIdx.x;
  const int tid = threadIdx.x;
  const float4 v = ((const float4*)(x + (size_t)row * 1024))[tid];
  float ss = v.x * v.x + v.y * v.y + v.z * v.z + v.w * v.w;
  ss += __shfl_xor(ss, 1, 64);
  ss += __shfl_xor(ss, 2, 64);
  ss += __shfl_xor(ss, 4, 64);
  ss += __shfl_xor(ss, 8, 64);
  ss += __shfl_xor(ss, 16, 64);
  ss += __shfl_xor(ss, 32, 64);
  if ((tid & 63) == 0) red[tid >> 6] = ss;
  __syncthreads();
  const float tot = red[0] + red[1] + red[2] + red[3];
  const float sc = rsqrtf(tot * (1.0f / 1024.0f) + 1e-6f);
  const float4 wv = ((const float4*)wt)[tid];
  ushort4 r;
  r.x = f2bf(v.x * sc * wv.x);
  r.y = f2bf(v.y * sc * wv.y);
  r.z = f2bf(v.z * sc * wv.z);
  r.w = f2bf(v.w * sc * wv.w);
  ((ushort4*)(o + (size_t)row * 1024))[tid] = r;
}

// ---------------------------------------------------------------------------
// GEMM: C[M,N] = A[M,K] @ B[N,K]^T   (A,B bf16 row-major, K-contiguous)
// 128x128 tile, BK=32, 4 waves (2x2 of 64x64), double-buffered LDS staged via
// global_load_lds width 16.  Epilogues:
//   0: store bf16            1: store sigmoid(c) bf16
//   2: store silu(c) bf16    3: store c * aux[idx] bf16   (aux bf16)
//   4: store c + resid[idx] fp32
// ---------------------------------------------------------------------------
template <int EPI>
__global__ __launch_bounds__(256) void gemm_bf16_k(
    const u16* __restrict__ A, const u16* __restrict__ B, int N, int K,
    u16* __restrict__ cb, float* __restrict__ cf,
    const u16* __restrict__ aux, const float* __restrict__ resid) {
  __shared__ __align__(16) u16 As[2][4096];   // 128 rows x 32 cols
  __shared__ __align__(16) u16 Bs[2][4096];

  const int tid = threadIdx.x;
  const int w = tid >> 6, lane = tid & 63;
  const int wm = w >> 1, wn = w & 1;
  const int g = lane >> 4, r16 = lane & 15;
  const int m0 = blockIdx.y * 128, n0 = blockIdx.x * 128;

  const int crow = lane >> 2;        // row within a 16-row staging chunk
  const int ccol = (lane & 3) * 8;   // element col within 32

  floatx4 acc[4][4];
#pragma unroll
  for (int i = 0; i < 4; i++)
#pragma unroll
    for (int j = 0; j < 4; j++) acc[i][j] = (floatx4){0.f, 0.f, 0.f, 0.f};

  const int nk = K >> 5;

  auto stage = [&](int buf, int k0) {
#pragma unroll
    for (int p = 0; p < 2; p++) {
      const int c = p * 4 + w;  // 8 chunks of 16 rows, 2 per wave
      gload16(A + (size_t)(m0 + c * 16 + crow) * K + k0 + ccol, &As[buf][c * 512]);
      gload16(B + (size_t)(n0 + c * 16 + crow) * K + k0 + ccol, &Bs[buf][c * 512]);
    }
  };

  stage(0, 0);
  __syncthreads();

  for (int kt = 0; kt < nk; ++kt) {
    const int buf = kt & 1;
    if (kt + 1 < nk) stage(buf ^ 1, (kt + 1) * 32);
    short8 af[4], bfr[4];
#pragma unroll
    for (int i = 0; i < 4; i++)
      af[i] = *(const short8*)&As[buf][(wm * 64 + i * 16 + r16) * 32 + g * 8];
#pragma unroll
    for (int j = 0; j < 4; j++)
      bfr[j] = *(const short8*)&Bs[buf][(wn * 64 + j * 16 + r16) * 32 + g * 8];
#pragma unroll
    for (int i = 0; i < 4; i++)
#pragma unroll
      for (int j = 0; j < 4; j++) acc[i][j] = mfma16(af[i], bfr[j], acc[i][j]);
    __syncthreads();
  }

#pragma unroll
  for (int i = 0; i < 4; i++) {
    const int row = m0 + wm * 64 + i * 16 + g * 4;
#pragma unroll
    for (int j = 0; j < 4; j++) {
      const int col = n0 + wn * 64 + j * 16 + r16;
#pragma unroll
      for (int rr = 0; rr < 4; rr++) {
        const float v = acc[i][j][rr];
        const size_t idx = (size_t)(row + rr) * N + col;
        if constexpr (EPI == 0)      cb[idx] = f2bf(v);
        else if constexpr (EPI == 1) cb[idx] = f2bf(1.0f / (1.0f + __expf(-v)));
        else if constexpr (EPI == 2) cb[idx] = f2bf(v / (1.0f + __expf(-v)));
        else if constexpr (EPI == 3) cb[idx] = f2bf(v * bf2f(aux[idx]));
        else                         cf[idx] = v + resid[idx];
      }
    }
  }
}

// ---------------------------------------------------------------------------
// Sliding-window causal attention (WINDOW=256) + fused sigmoid-gate multiply.
// Block = (q-block of 64, head, batch), 4 waves x 16 query rows.
// qkv layout per token: [q(1024) | k(1024) | v(1024)], head h at +h*64.
// K staged in LDS [64][80] (16B-aligned rows, <=4-way bank alias);
// V staged transposed Vt[d][key]; P routed through LDS to become an A-frag.
// ---------------------------------------------------------------------------
__global__ __launch_bounds__(256) void attn_win_kernel(
    const u16* __restrict__ qkv, const u16* __restrict__ gate,
    u16* __restrict__ out) {
  __shared__ __align__(16) u16 Kl[64][80];
  __shared__ __align__(16) u16 Vt[64][80];
  __shared__ __align__(16) u16 Pl[4][16][80];

  const int tid = threadIdx.x;
  const int w = tid >> 6, lane = tid & 63;
  const int g = lane >> 4, r16 = lane & 15;

  const int q0 = blockIdx.x * 64;
  const int h = blockIdx.y;
  const int b = blockIdx.z;
  const u16* qb_ = qkv + (size_t)b * 2048 * 3072;

  // Q A-frags for this wave: rows tq = q0 + w*16 + r16, k-dim = head dim d
  const int tq = q0 + w * 16 + r16;
  const u16* qptr = qb_ + (size_t)tq * 3072 + h * 64;
  const short8 aq0 = *(const short8*)(qptr + g * 8);
  const short8 aq1 = *(const short8*)(qptr + 32 + g * 8);

  floatx4 O[4] = {{0,0,0,0},{0,0,0,0},{0,0,0,0},{0,0,0,0}};
  float mrow[4] = {-1e30f, -1e30f, -1e30f, -1e30f};
  float lrow[4] = {0.f, 0.f, 0.f, 0.f};

  const int srow = tid >> 2;       // staging: 64 rows
  const int sq4 = tid & 3;         // 4 x 16B per row
  const int qw = q0 + w * 16;

  for (int kt = q0 - 256; kt <= q0; kt += 64) {
    if (kt < 0) continue;
    {  // ---- stage K and V^T ----
      const u16* kb = qb_ + (size_t)(kt + srow) * 3072 + 1024 + h * 64 + sq4 * 16;
      const short8 kv0 = *(const short8*)kb;
      const short8 kv1 = *(const short8*)(kb + 8);
      *(short8*)&Kl[srow][sq4 * 16] = kv0;
      *(short8*)&Kl[srow][sq4 * 16 + 8] = kv1;
      const u16* vb = kb + 1024;
      const short8 vv0 = *(const short8*)vb;
      const short8 vv1 = *(const short8*)(vb + 8);
#pragma unroll
      for (int j = 0; j < 8; j++) Vt[sq4 * 16 + j][srow] = (u16)vv0[j];
#pragma unroll
      for (int j = 0; j < 8; j++) Vt[sq4 * 16 + 8 + j][srow] = (u16)vv1[j];
    }
    __syncthreads();

    const bool active = (qw + 15 >= kt) && (qw - kt < 319);
    if (active) {
      // ---- S = Q K^T (16 x 64), raw scores; scale folded into exp ----
      floatx4 S[4];
#pragma unroll
      for (int nf = 0; nf < 4; nf++) {
        const short8 bk0 = *(const short8*)&Kl[nf * 16 + r16][g * 8];
        const short8 bk1 = *(const short8*)&Kl[nf * 16 + r16][32 + g * 8];
        floatx4 a = {0.f, 0.f, 0.f, 0.f};
        a = mfma16(aq0, bk0, a);
        a = mfma16(aq1, bk1, a);
        S[nf] = a;
      }
      // ---- mask + online softmax ----
      float pm[4][4];
      float nmax[4] = {-1e30f, -1e30f, -1e30f, -1e30f};
#pragma unroll
      for (int nf = 0; nf < 4; nf++) {
        const int key = kt + nf * 16 + r16;
#pragma unroll
        for (int rr = 0; rr < 4; rr++) {
          const int q = qw + g * 4 + rr;
          const int dist = q - key;
          const float s = (dist >= 0 && dist < 256) ? S[nf][rr] : -1e30f;
          pm[nf][rr] = s;
          nmax[rr] = fmaxf(nmax[rr], s);
        }
      }
#pragma unroll
      for (int rr = 0; rr < 4; rr++) {
        float v = nmax[rr];
        v = fmaxf(v, __shfl_xor(v, 1, 64));
        v = fmaxf(v, __shfl_xor(v, 2, 64));
        v = fmaxf(v, __shfl_xor(v, 4, 64));
        v = fmaxf(v, __shfl_xor(v, 8, 64));
        const float mnew = fmaxf(mrow[rr], v);
        const float alpha = __expf(0.125f * (mrow[rr] - mnew));
        mrow[rr] = mnew;
        lrow[rr] *= alpha;
#pragma unroll
        for (int n = 0; n < 4; n++) O[n][rr] *= alpha;
        float ls = 0.f;
#pragma unroll
        for (int nf = 0; nf < 4; nf++) {
          const float s = pm[nf][rr];
          const float pv = (s < -1e29f) ? 0.f : __expf(0.125f * (s - mnew));
          pm[nf][rr] = pv;
          ls += pv;
        }
        ls += __shfl_xor(ls, 1, 64);
        ls += __shfl_xor(ls, 2, 64);
        ls += __shfl_xor(ls, 4, 64);
        ls += __shfl_xor(ls, 8, 64);
        lrow[rr] += ls;
      }
      // ---- P -> LDS (layout change S-frag -> A-frag), then PV ----
#pragma unroll
      for (int nf = 0; nf < 4; nf++)
#pragma unroll
        for (int rr = 0; rr < 4; rr++)
          Pl[w][g * 4 + rr][nf * 16 + r16] = f2bf(pm[nf][rr]);
#pragma unroll
      for (int kf = 0; kf < 2; kf++) {
        const short8 pa = *(const short8*)&Pl[w][r16][kf * 32 + g * 8];
#pragma unroll
        for (int n = 0; n < 4; n++) {
          const short8 vb8 = *(const short8*)&Vt[n * 16 + r16][kf * 32 + g * 8];
          O[n] = mfma16(pa, vb8, O[n]);
        }
      }
    }
    __syncthreads();
  }

  // ---- epilogue: normalize, multiply by sigmoid-gate (precomputed bf16) ----
#pragma unroll
  for (int n = 0; n < 4; n++) {
#pragma unroll
    for (int rr = 0; rr < 4; rr++) {
      const int t = qw + g * 4 + rr;
      const size_t idx = ((size_t)(b * 2048 + t)) * 1024 + h * 64 + n * 16 + r16;
      const float gv = bf2f(gate[idx]);
      const float ov = (O[n][rr] / lrow[rr]) * gv;
      out[idx] = f2bf(ov);
    }
  }
}

// ---------------------------------------------------------------------------
// Orchestration.  ws layout (u16 elements unless noted), ~138 MB total:
//   weights bf16 (17.8M) | xn 4M | qkv 12M | gates 4M | a3 4M | h 4M |
//   gs 16M | x2 (fp32, 4M floats)
// ---------------------------------------------------------------------------
extern "C" void kernel_launch(void* const* d_in, const int* in_sizes, int n_in,
                              void* d_out, int out_size, void* d_ws,
                              size_t ws_size, hipStream_t stream) {
  (void)in_sizes; (void)n_in; (void)out_size; (void)ws_size;
  const float* x     = (const float*)d_in[0];
  const float* ln1   = (const float*)d_in[1];
  const float* qkvw  = (const float*)d_in[2];
  const float* gatew = (const float*)d_in[3];
  const float* outw  = (const float*)d_in[4];
  const float* ln2   = (const float*)d_in[5];
  const float* wg    = (const float*)d_in[6];
  const float* wu    = (const float*)d_in[7];
  const float* wo    = (const float*)d_in[8];
  float* outp = (float*)d_out;

  u16* p = (u16*)d_ws;
  u16* qkvw_b  = p; p += 3 * 1024 * 1024;
  u16* gatew_b = p; p += 1024 * 1024;
  u16* outw_b  = p; p += 1024 * 1024;
  u16* wg_b    = p; p += 4 * 1024 * 1024;
  u16* wu_b    = p; p += 4 * 1024 * 1024;
  u16* wo_b    = p; p += 4 * 1024 * 1024;
  u16* xn      = p; p += 4096 * 1024;
  u16* qkvb    = p; p += (size_t)4096 * 3072;
  u16* gates   = p; p += 4096 * 1024;
  u16* a3      = p; p += 4096 * 1024;
  u16* hb      = p; p += 4096 * 1024;
  u16* gs      = p; p += (size_t)4096 * 4096;
  float* x2    = (float*)p;

  // weight conversion fp32 -> bf16
  cvt_k<<<3072, 256, 0, stream>>>(qkvw, qkvw_b);
  cvt_k<<<1024, 256, 0, stream>>>(gatew, gatew_b);
  cvt_k<<<1024, 256, 0, stream>>>(outw, outw_b);
  cvt_k<<<4096, 256, 0, stream>>>(wg, wg_b);
  cvt_k<<<4096, 256, 0, stream>>>(wu, wu_b);
  cvt_k<<<4096, 256, 0, stream>>>(wo, wo_b);

  // x_n = rmsnorm(x, ln1)  -> bf16
  rmsnorm_k<<<4096, 256, 0, stream>>>(x, ln1, xn);

  // qkv = x_n @ qkv_w.T (bf16 out);  gates = sigmoid(x_n @ gate_w.T) (bf16)
  gemm_bf16_k<0><<<dim3(24, 32), 256, 0, stream>>>(xn, qkvw_b, 3072, 1024,
                                                   qkvb, nullptr, nullptr, nullptr);
  gemm_bf16_k<1><<<dim3(8, 32), 256, 0, stream>>>(xn, gatew_b, 1024, 1024,
                                                  gates, nullptr, nullptr, nullptr);

  // a3 = attention(q,k,v) * gates   (bf16)
  attn_win_kernel<<<dim3(32, 16, 2), 256, 0, stream>>>(qkvb, gates, a3);

  // x2 = x + a3 @ out_w.T  (fp32)
  gemm_bf16_k<4><<<dim3(8, 32), 256, 0, stream>>>(a3, outw_b, 1024, 1024,
                                                  nullptr, x2, nullptr, x);

  // h = rmsnorm(x2, ln2) -> bf16
  rmsnorm_k<<<4096, 256, 0, stream>>>(x2, ln2, hb);

  // gs = silu(h @ wg.T);  gs = gs * (h @ wu.T)  [aliased elementwise epilogue]
  gemm_bf16_k<2><<<dim3(32, 32), 256, 0, stream>>>(hb, wg_b, 4096, 1024,
                                                   gs, nullptr, nullptr, nullptr);
  gemm_bf16_k<3><<<dim3(32, 32), 256, 0, stream>>>(hb, wu_b, 4096, 1024,
                                                   gs, nullptr, gs, nullptr);

  // out = x2 + gs @ wo.T  (fp32, final)
  gemm_bf16_k<4><<<dim3(8, 32), 256, 0, stream>>>(gs, wo_b, 1024, 4096,
                                                  nullptr, outp, nullptr, x2);
}